// Round 11
// baseline (318.258 us; speedup 1.0000x reference)
//
#include <hip/hip_runtime.h>

typedef __bf16 bf16;
typedef __bf16 bf16x8 __attribute__((ext_vector_type(8)));
typedef __bf16 bf16x4 __attribute__((ext_vector_type(4)));
typedef _Float16 f16;
typedef _Float16 f16x2 __attribute__((ext_vector_type(2)));
typedef _Float16 f16x4 __attribute__((ext_vector_type(4)));
typedef _Float16 f16x8 __attribute__((ext_vector_type(8)));
typedef __fp16 h16x2 __attribute__((ext_vector_type(2)));  // cvt_pkrtz return type
typedef float f32x4 __attribute__((ext_vector_type(4)));

__device__ __forceinline__ f32x4 mfma_qk(bf16x8 a, bf16x8 b, f32x4 c) {
    return __builtin_amdgcn_mfma_f32_16x16x32_bf16(a, b, c, 0, 0, 0);
}
// full-rate K=32 f16 MFMA for PV (legacy 16x16x16 runs at half rate)
__device__ __forceinline__ f32x4 mfma_pv32(f16x8 a, f16x8 b, f32x4 c) {
    return __builtin_amdgcn_mfma_f32_16x16x32_f16(a, b, c, 0, 0, 0);
}
// pack two f32 -> f16x2 via v_cvt_pkrtz (bit-identical retype of __fp16 result)
__device__ __forceinline__ f16x2 pkrtz(float a, float b) {
    h16x2 r = __builtin_amdgcn_cvt_pkrtz(a, b);
    return __builtin_bit_cast(f16x2, r);
}

// async global -> LDS, 16 bytes per lane (dest = wave-uniform base + lane*16)
#define GLOAD_LDS16(gp, lp)                                                    \
    __builtin_amdgcn_global_load_lds(                                          \
        (const __attribute__((address_space(1))) unsigned int*)(gp),           \
        (__attribute__((address_space(3))) unsigned int*)(lp), 16, 0, 0)

// counted pipeline waits: oldest stage complete, newest stays in flight.
// NEVER vmcnt(0) in a main loop (T4).
#define PWAIT4 asm volatile("s_waitcnt vmcnt(4) lgkmcnt(0)\ns_barrier" ::: "memory")
#define PWAIT3 asm volatile("s_waitcnt vmcnt(3) lgkmcnt(0)\ns_barrier" ::: "memory")
#define PWAIT2 asm volatile("s_waitcnt vmcnt(2) lgkmcnt(0)\ns_barrier" ::: "memory")
#define PWAIT0 asm volatile("s_waitcnt vmcnt(0) lgkmcnt(0)\ns_barrier" ::: "memory")

// ---------------------------------------------------------------------------
// Cast fp32 -> bf16: 4 weights (1024^2 each), key_value (8M), query (8M).
// Wq is pre-scaled by 1/sqrt(HD)=0.125 (EXACT in bf16: exponent shift).
// R11: grid-stride x4 (5120 blocks) — 20480 tiny blocks ran at 3.6 TB/s,
// launch/sched overhead; fewer, fatter blocks amortize it.
// ---------------------------------------------------------------------------
__global__ __launch_bounds__(256) void cast_inputs(
    const float* __restrict__ w0, const float* __restrict__ w1,
    const float* __restrict__ w2, const float* __restrict__ w3,
    const float* __restrict__ kv, const float* __restrict__ q,
    bf16* __restrict__ Wb, bf16* __restrict__ KVa, bf16* __restrict__ Qb) {
    for (long i4 = (long)blockIdx.x * 256 + threadIdx.x; i4 < 5242880;
         i4 += 5120l * 256) {
        const float* src;
        bf16* dst;
        long loc;
        float sc = 1.0f;
        if (i4 < 1048576) {            // 4 weights x 262144 float4
            int which = (int)(i4 >> 18);
            loc = (i4 & 262143) << 2;
            src = which == 0 ? w0 : which == 1 ? w1 : which == 2 ? w2 : w3;
            dst = Wb + ((long)which << 20);
            if (which == 0) sc = 0.125f;
        } else if (i4 < 3145728) {     // key_value
            loc = (i4 - 1048576) << 2;
            src = kv; dst = KVa;
        } else {                       // query
            loc = (i4 - 3145728) << 2;
            src = q; dst = Qb;
        }
        float4 f = *(const float4*)(src + loc);
        bf16x4 o;
        o[0] = (bf16)(f.x * sc); o[1] = (bf16)(f.y * sc);
        o[2] = (bf16)(f.z * sc); o[3] = (bf16)(f.w * sc);
        *(bf16x4*)(dst + loc) = o;
    }
}

// ---------------------------------------------------------------------------
// Core GEMM: C[M,N] = A[M,K] @ W[N,K]^T + bias*bsc. M=8192, N=K=1024.
// Triple-buffered counted-vmcnt pipeline (BK=32, 3 x 16KB buffers, 48KB LDS,
// 3 blocks/CU). Per step: PWAIT4 ; stage(t+2) ; compute(t) — loads stay in
// flight across barriers. At ~500 TF this is the 128²/2-barrier structure's
// documented ceiling for these shapes (m93: 517); R6/R9/R10 schedule
// variants were all within ±2 µs of each other.
// LDS layout per buffer b (byte base b*16384): A slot(r,c4)=r*4+(c4^(r&3)),
//   16B slots; B at +8192. Fragment chunk for k=quad*8+j is slot quad^(r&3).
// om: 0 = bf16 row-major, 1 = f32 row-major,
// om: 2 = f16 V^T [b,h,d,skv] with kv PERMUTED per 32-block:
//         chunk g (g=0..3) holds kv = 32B + {4g..4g+3, 16+4g..16+4g+3}
//         so the attn PV A-fragment is a single contiguous f16x8.
// ---------------------------------------------------------------------------
__device__ __forceinline__ void gemm_core(
    const bf16* __restrict__ A, const bf16* __restrict__ Wt,
    const float* __restrict__ bias, void* __restrict__ Yv,
    const int om, bf16* smem, const int n0, const int m0, const float bsc) {
    constexpr int Kd = 1024, Nd = 1024;
    constexpr int TP = 132;  // om2 transpose row stride
    char* sbytes = (char*)smem;
    const int tid = threadIdx.x;
    const int wid = tid >> 6, lane = tid & 63;
    const int l16 = lane & 15, quad = lane >> 4;
    const int mh = (wid >> 1) * 64, nh = (wid & 1) * 64;

    const int rS = tid >> 2;
    const int cS = (tid & 3) ^ (rS & 3);
    const bf16* Asrc = A + (long)(m0 + rS) * Kd + cS * 8;
    const bf16* Bsrc = Wt + (long)(n0 + rS) * Kd + cS * 8;

    const int aOff = (mh + l16) * 64 + ((quad ^ (l16 & 3)) << 4);
    const int bOff = 8192 + (nh + l16) * 64 + ((quad ^ (l16 & 3)) << 4);

    f32x4 acc[4][4];
#pragma unroll
    for (int i = 0; i < 4; ++i)
#pragma unroll
        for (int j = 0; j < 4; ++j) acc[i][j] = (f32x4){0.f, 0.f, 0.f, 0.f};

    auto stageK = [&](int step, int b) {
        const int kt = step * 32;
        char* base = sbytes + b * 16384;
        GLOAD_LDS16(Asrc + kt, base + tid * 16);
        GLOAD_LDS16(Asrc + 64 * Kd + kt, base + 4096 + tid * 16);
        GLOAD_LDS16(Bsrc + kt, base + 8192 + tid * 16);
        GLOAD_LDS16(Bsrc + 64 * Kd + kt, base + 12288 + tid * 16);
    };

    auto computeK = [&](int b) {
        const char* base = sbytes + b * 16384;
        bf16x8 af[4], bq[4];
#pragma unroll
        for (int i = 0; i < 4; ++i) af[i] = *(const bf16x8*)(base + aOff + i * 1024);
#pragma unroll
        for (int i = 0; i < 4; ++i) bq[i] = *(const bf16x8*)(base + bOff + i * 1024);
#pragma unroll
        for (int i = 0; i < 4; ++i)
#pragma unroll
            for (int j = 0; j < 4; ++j)
                acc[i][j] = mfma_qk(af[i], bq[j], acc[i][j]);
    };

    stageK(0, 0);
    stageK(1, 1);
#pragma unroll 1
    for (int t = 0; t < 30; t += 3) {
        PWAIT4; stageK(t + 2, 2); computeK(0);
        PWAIT4; stageK(t + 3, 0); computeK(1);
        PWAIT4; stageK(t + 4, 1); computeK(2);
    }
    PWAIT4; computeK(0);   // step 30; step 31's loads in flight
    PWAIT0; computeK(1);   // step 31
    __syncthreads();       // all LDS reads done before epilogue overlay

    if (om == 2) {
#pragma unroll
        for (int j = 0; j < 4; ++j) {
            const int col = nh + j * 16 + l16;
            const float bv = bias[n0 + col] * bsc;
#pragma unroll
            for (int i = 0; i < 4; ++i)
#pragma unroll
                for (int p = 0; p < 2; ++p) {
                    f16x2 pk2;
                    pk2[0] = (f16)(acc[i][j][p * 2 + 0] + bv);
                    pk2[1] = (f16)(acc[i][j][p * 2 + 1] + bv);
                    *(f16x2*)&smem[col * TP + mh + i * 16 + quad * 4 + p * 2] = pk2;
                }
        }
        __syncthreads();
        const int b_ = m0 >> 11, skv0 = m0 & 2047;
        const int rowc = tid & 15;
        const int B32 = (rowc >> 2) * 32, g4 = (rowc & 3) * 4;
        const f16* sm = (const f16*)smem;
#pragma unroll
        for (int c = 0; c < 8; ++c) {
            const int col = (tid >> 4) + c * 16;
            const int colg = n0 + col;
            f16x4 lo = *(const f16x4*)&sm[col * TP + B32 + g4];
            f16x4 hi = *(const f16x4*)&sm[col * TP + B32 + 16 + g4];
            f16x8 v = __builtin_shufflevector(lo, hi, 0, 1, 2, 3, 4, 5, 6, 7);
            const long base = ((long)((b_ * 16 + (colg >> 6)) * 64 + (colg & 63))) << 11;
            *(f16x8*)((f16*)Yv + base + skv0 + rowc * 8) = v;
        }
    } else {
#pragma unroll
        for (int j = 0; j < 4; ++j) {
            const int col = n0 + nh + j * 16 + l16;
            const float bv = bias[col] * bsc;
#pragma unroll
            for (int i = 0; i < 4; ++i)
#pragma unroll
                for (int r = 0; r < 4; ++r) {
                    int row = m0 + mh + i * 16 + quad * 4 + r;
                    float v = acc[i][j][r] + bv;
                    if (om == 1)
                        ((float*)Yv)[(long)row * Nd + col] = v;
                    else
                        ((bf16*)Yv)[(long)row * Nd + col] = (bf16)v;
                }
        }
    }
}

// Fused Q/K/V projections: one 1536-block launch. Chunked bijective XCD
// swizzle keeps A-panel / W reuse in one L2. 48KB LDS -> 3 blocks/CU.
__global__ __launch_bounds__(256) void proj_qkv(
    const bf16* __restrict__ Qb, const bf16* __restrict__ KVa,
    const bf16* __restrict__ Wb,
    const float* __restrict__ bq, const float* __restrict__ bk,
    const float* __restrict__ bv,
    bf16* __restrict__ Qw, bf16* __restrict__ Kw, f16* __restrict__ Vt) {
    __shared__ __align__(16) bf16 smem[24576];  // 49152 B: 3 pipeline bufs / TP overlay
    const int lin = blockIdx.x + (blockIdx.y << 3) + (blockIdx.z << 9);  // 0..1535
    const int nid = (lin & 7) * 192 + (lin >> 3);
    const int z = nid >> 9, rem = nid & 511;
    const int n0 = (rem & 7) << 7, m0 = (rem >> 3) << 7;
    if (z == 0)
        gemm_core(Qb, Wb, bq, Qw, 0, smem, n0, m0, 0.125f);  // Wq pre-scaled
    else if (z == 1)
        gemm_core(KVa, Wb + (1l << 20), bk, Kw, 0, smem, n0, m0, 1.0f);
    else
        gemm_core(KVa, Wb + (2l << 20), bv, Vt, 2, smem, n0, m0, 1.0f);
}

// ---------------------------------------------------------------------------
// gemm_o: out[8192,1024] f32 = Cw @ Wo^T + bo.
// R11: tile 128x64 -> 1024 blocks = 4 blocks/CU (was 512 = 2/CU — the
// worst-occupancy kernel, ~246 TF vs proj's ~500 with the same inner loop).
// 4 waves, each 64x32 (acc 4x2). BK=32, 3 x 12KB buffers (36KB LDS, 4/CU:
// 144<160KB). Stage = 3 gloads (A 8KB, B 4KB); PWAIT3 counted pipeline.
// ---------------------------------------------------------------------------
__global__ __launch_bounds__(256) void gemm_o(
    const bf16* __restrict__ Cw, const bf16* __restrict__ Wo,
    const float* __restrict__ bo, float* __restrict__ out) {
    constexpr int Kd = 1024, Nd = 1024;
    __shared__ __align__(16) char sb[36864];  // 3 x 12KB
    const int tid = threadIdx.x;
    const int wid = tid >> 6, lane = tid & 63;
    const int l16 = lane & 15, quad = lane >> 4;
    // 1024 blocks, chunked bijective XCD swizzle (128/XCD); consecutive nid
    // share the m-panel -> A reuse within one XCD L2.
    const int lin = blockIdx.x + (blockIdx.y << 4);  // grid (16,64)
    const int nid = (lin & 7) * 128 + (lin >> 3);
    const int n0 = (nid & 15) << 6, m0 = (nid >> 4) << 7;
    const int mh = (wid >> 1) * 64, nh = (wid & 1) * 32;

    const int rS = tid >> 2;                  // 0..63
    const int cS = (tid & 3) ^ (rS & 3);
    const bf16* Asrc = Cw + (long)(m0 + rS) * Kd + cS * 8;
    const bf16* Bsrc = Wo + (long)(n0 + rS) * Kd + cS * 8;  // 64 rows

    const int aOff = (mh + l16) * 64 + ((quad ^ (l16 & 3)) << 4);
    const int bOff = 8192 + (nh + l16) * 64 + ((quad ^ (l16 & 3)) << 4);

    f32x4 acc[4][2];
#pragma unroll
    for (int i = 0; i < 4; ++i)
#pragma unroll
        for (int j = 0; j < 2; ++j) acc[i][j] = (f32x4){0.f, 0.f, 0.f, 0.f};

    auto stageK = [&](int step, int b) {
        const int kt = step * 32;
        char* base = sb + b * 12288;
        GLOAD_LDS16(Asrc + kt, base + tid * 16);
        GLOAD_LDS16(Asrc + 64 * Kd + kt, base + 4096 + tid * 16);
        GLOAD_LDS16(Bsrc + kt, base + 8192 + tid * 16);
    };

    auto computeK = [&](int b) {
        const char* base = sb + b * 12288;
        bf16x8 af[4], bq[2];
#pragma unroll
        for (int i = 0; i < 4; ++i) af[i] = *(const bf16x8*)(base + aOff + i * 1024);
#pragma unroll
        for (int i = 0; i < 2; ++i) bq[i] = *(const bf16x8*)(base + bOff + i * 1024);
#pragma unroll
        for (int i = 0; i < 4; ++i)
#pragma unroll
            for (int j = 0; j < 2; ++j)
                acc[i][j] = mfma_qk(af[i], bq[j], acc[i][j]);
    };

    stageK(0, 0);
    stageK(1, 1);
#pragma unroll 1
    for (int t = 0; t < 30; t += 3) {
        PWAIT3; stageK(t + 2, 2); computeK(0);
        PWAIT3; stageK(t + 3, 0); computeK(1);
        PWAIT3; stageK(t + 4, 1); computeK(2);
    }
    PWAIT3; computeK(0);   // step 30; step 31's loads in flight
    PWAIT0; computeK(1);   // step 31

    // epilogue: f32 row-major stores
#pragma unroll
    for (int j = 0; j < 2; ++j) {
        const int col = n0 + nh + j * 16 + l16;
        const float bv = bo[col];
#pragma unroll
        for (int i = 0; i < 4; ++i)
#pragma unroll
            for (int r = 0; r < 4; ++r) {
                int row = m0 + mh + i * 16 + quad * 4 + r;
                out[(long)row * Nd + col] = acc[i][j][r] + bv;
            }
    }
}

// ---------------------------------------------------------------------------
// StableMax cross-attention, transposed-score formulation.
// Attn = the R6 kernel (106-108 µs measured best). R8's rcp-combine was a
// cycle-accounting wash (rcp 128->32 cyc but +104 cyc muls/adds + serial
// chain -> 117.8). Do not re-try VALU restructures without an issue-cycle
// budget showing >20% net cut.
// Structure: KVB=32, triple-buffered depth-2 pipeline, vmcnt(2) counted
// waits, 24KB LDS, zero-VALU LDS addressing, pkrtz P-pack, ones-MFMA den,
// scores pre-scaled via Wq/8.
// NOTE: plain __launch_bounds__(256) — adding ",4" min-occupancy clamped the
// allocator to 64 VGPRs and spilled to scratch (R1: 1.2GB HBM writes, 4x
// slowdown). Do not re-add.
// ---------------------------------------------------------------------------
__global__ __launch_bounds__(256) void attn_kernel(
    const bf16* __restrict__ Q, const bf16* __restrict__ K,
    const f16* __restrict__ Vt, bf16* __restrict__ C) {
    constexpr int E = 1024, S = 2048;
    __shared__ __align__(16) char smem_raw[24576];  // 3 bufs x (4KB K + 4KB V)

    const int tid = threadIdx.x;
    const int wid = tid >> 6, lane = tid & 63;
    const int l16 = lane & 15, quad = lane >> 4;
    const int l7 = l16 & 7, l3 = l16 & 3;
    const int lin = blockIdx.x + (blockIdx.y << 4) + (blockIdx.z << 8);
    const int nid = (lin & 7) * 128 + (lin >> 3);
    const int qt = nid & 15, h = (nid >> 4) & 15, b = nid >> 8;

    const long q0 = (long)b * S + qt * 128;
    const bf16* Qg = Q + q0 * E + h * 64;
    const bf16* Kg = K + (long)b * S * E + h * 64;
    const f16* Vg = Vt + ((long)(b * 16 + h) << 17);  // [64 d][2048 kv] permuted

    bf16x8 qf[2][2];
#pragma unroll
    for (int mt = 0; mt < 2; ++mt)
#pragma unroll
        for (int kc = 0; kc < 2; ++kc)
            qf[mt][kc] = *(const bf16x8*)(Qg + (long)(wid * 32 + mt * 16 + l16) * E + kc * 32 + quad * 8);
    asm volatile("s_waitcnt vmcnt(0)" ::: "memory");

    const bf16* Ksrc = Kg + (long)(tid >> 3) * E + (((tid & 7) ^ ((tid >> 3) & 7)) * 8);
    const f16* Vsrc = Vg + (long)(tid >> 2) * S + (((tid & 3) ^ ((tid >> 2) & 3)) * 8);

    int ka0[3], ka1[3], va[3];
#pragma unroll
    for (int i = 0; i < 3; ++i) {
        ka0[i] = i * 8192 + l16 * 128 + ((quad ^ l7) << 4);
        ka1[i] = i * 8192 + l16 * 128 + (((quad + 4) ^ l7) << 4);
        va[i]  = i * 8192 + 4096 + l16 * 64 + ((quad ^ l3) << 4);
    }

    f16x8 ones8;
#pragma unroll
    for (int j = 0; j < 8; ++j) ones8[j] = (f16)1.0f;

    f32x4 ctx[2][4];   // ctx^T: lane holds d=dt*16+quad*4+r, q=l16
    f32x4 dacc[2];     // ones-MFMA denominator accumulator (rows identical)
#pragma unroll
    for (int mt = 0; mt < 2; ++mt) {
        dacc[mt] = (f32x4){0.f, 0.f, 0.f, 0.f};
#pragma unroll
        for (int dt = 0; dt < 4; ++dt) ctx[mt][dt] = (f32x4){0.f, 0.f, 0.f, 0.f};
    }

    auto stage = [&](int kv0, int bi) {
        GLOAD_LDS16(Ksrc + (long)kv0 * E, smem_raw + bi * 8192 + tid * 16);
        GLOAD_LDS16(Vsrc + kv0, smem_raw + bi * 8192 + 4096 + tid * 16);
    };

    auto compute = [&](int bi) {
        f32x4 sacc[2][2];  // [sh][mt]
#pragma unroll
        for (int sh = 0; sh < 2; ++sh) {
            bf16x8 kf0 = *(const bf16x8*)(smem_raw + ka0[bi] + sh * 2048);
            bf16x8 kf1 = *(const bf16x8*)(smem_raw + ka1[bi] + sh * 2048);
            __builtin_amdgcn_s_setprio(1);
#pragma unroll
            for (int mt = 0; mt < 2; ++mt) {
                f32x4 t = mfma_qk(kf0, qf[mt][0], (f32x4){0.f, 0.f, 0.f, 0.f});
                sacc[sh][mt] = mfma_qk(kf1, qf[mt][1], t);
            }
            __builtin_amdgcn_s_setprio(0);
        }
        f16x8 pp[2];
#pragma unroll
        for (int mt = 0; mt < 2; ++mt) {
            float sv[8];
#pragma unroll
            for (int sh = 0; sh < 2; ++sh)
#pragma unroll
                for (int r = 0; r < 4; ++r) {
                    float x = sacc[sh][mt][r];
                    float u = __builtin_fabsf(x) + 1.0f;
                    sv[sh * 4 + r] = (x >= 0.f) ? u : __builtin_amdgcn_rcpf(u);
                }
            f16x2 w0 = pkrtz(sv[0], sv[1]);
            f16x2 w1 = pkrtz(sv[2], sv[3]);
            f16x2 w2 = pkrtz(sv[4], sv[5]);
            f16x2 w3 = pkrtz(sv[6], sv[7]);
            f16x4 lo = __builtin_shufflevector(w0, w1, 0, 1, 2, 3);
            f16x4 hi = __builtin_shufflevector(w2, w3, 0, 1, 2, 3);
            pp[mt] = __builtin_shufflevector(lo, hi, 0, 1, 2, 3, 4, 5, 6, 7);
        }
        __builtin_amdgcn_s_setprio(1);
        dacc[0] = mfma_pv32(ones8, pp[0], dacc[0]);
        dacc[1] = mfma_pv32(ones8, pp[1], dacc[1]);
        __builtin_amdgcn_s_setprio(0);
#pragma unroll
        for (int dt = 0; dt < 4; ++dt) {
            f16x8 vf = *(const f16x8*)(smem_raw + va[bi] + dt * 1024);
            __builtin_amdgcn_s_setprio(1);
#pragma unroll
            for (int mt = 0; mt < 2; ++mt)
                ctx[mt][dt] = mfma_pv32(vf, pp[mt], ctx[mt][dt]);
            __builtin_amdgcn_s_setprio(0);
        }
    };

    stage(0, 0);
    stage(32, 1);
    int kv = 64;
#pragma unroll 1
    for (int it = 0; it < 20; ++it) {
        PWAIT2; stage(kv, 2); compute(0); kv += 32;
        PWAIT2; stage(kv, 0); compute(1); kv += 32;
        PWAIT2; stage(kv, 1); compute(2); kv += 32;
    }
    PWAIT2; stage(kv, 2); compute(0);        // t=60, stage tile 62
    PWAIT2; stage(kv + 32, 0); compute(1);   // t=61, stage tile 63
    PWAIT2; compute(2);                      // t=62
    PWAIT0; compute(0);                      // t=63
    __syncthreads();

    float scl[2];
#pragma unroll
    for (int mt = 0; mt < 2; ++mt) scl[mt] = __builtin_amdgcn_rcpf(dacc[mt][0]);

    bf16* Os = (bf16*)smem_raw;
#pragma unroll
    for (int mt = 0; mt < 2; ++mt)
#pragma unroll
        for (int dt = 0; dt < 4; ++dt) {
            bf16x4 o;
#pragma unroll
            for (int r = 0; r < 4; ++r) o[r] = (bf16)(ctx[mt][dt][r] * scl[mt]);
            *(bf16x4*)&Os[(wid * 32 + mt * 16 + l16) * 68 + dt * 16 + quad * 4] = o;
        }
    __syncthreads();
    {
        const int r = tid >> 1, c = (tid & 1) * 32;
        bf16* cp = C + (q0 + r) * E + h * 64 + c;
#pragma unroll
        for (int j = 0; j < 4; ++j)
            *(bf16x8*)(cp + j * 8) = *(const bf16x8*)&Os[r * 68 + c + j * 8];
    }
}

// ---------------------------------------------------------------------------
extern "C" void kernel_launch(void* const* d_in, const int* in_sizes, int n_in,
                              void* d_out, int out_size, void* d_ws, size_t ws_size,
                              hipStream_t stream) {
    const float* query = (const float*)d_in[0];
    const float* keyv  = (const float*)d_in[1];
    const float* Wq = (const float*)d_in[2];
    const float* bq = (const float*)d_in[3];
    const float* Wk = (const float*)d_in[4];
    const float* bk = (const float*)d_in[5];
    const float* Wv = (const float*)d_in[6];
    const float* bv = (const float*)d_in[7];
    const float* Wo = (const float*)d_in[8];
    const float* bo = (const float*)d_in[9];

    char* ws = (char*)d_ws;
    bf16* Wb  = (bf16*)ws;                  // 8 MB: Wq/8,Wk,Wv,Wo bf16
    bf16* KVa = (bf16*)(ws + (8l << 20));   // 16 MB kv bf16 (later Cw)
    bf16* Qb  = (bf16*)(ws + (24l << 20));  // 16 MB query bf16
    bf16* Qw  = (bf16*)(ws + (40l << 20));  // 16 MB (holds q/8)
    f16*  Vt  = (f16*)(ws + (56l << 20));   // 16 MB V^T f16 [b,h,d,skv] permuted
    bf16* Kw  = (bf16*)d_out;               // d_out dead until gemm_o: use as Kw
    bf16* Cw  = KVa;                        // alias: KVa dead after proj_qkv

    cast_inputs<<<5120, 256, 0, stream>>>(Wq, Wk, Wv, Wo, keyv, query, Wb, KVa, Qb);

    proj_qkv<<<dim3(8, 64, 3), 256, 0, stream>>>(Qb, KVa, Wb, bq, bk, bv, Qw, Kw, Vt);

    attn_kernel<<<dim3(16, 16, 4), 256, 0, stream>>>(Qw, Kw, Vt, Cw);

    gemm_o<<<dim3(16, 64), 256, 0, stream>>>(Cw, Wb + (3l << 20), bo, (float*)d_out);
}

// Round 12
// 306.075 us; speedup vs baseline: 1.0398x; 1.0398x over previous
//
#include <hip/hip_runtime.h>

typedef __bf16 bf16;
typedef __bf16 bf16x8 __attribute__((ext_vector_type(8)));
typedef __bf16 bf16x4 __attribute__((ext_vector_type(4)));
typedef _Float16 f16;
typedef _Float16 f16x2 __attribute__((ext_vector_type(2)));
typedef _Float16 f16x4 __attribute__((ext_vector_type(4)));
typedef _Float16 f16x8 __attribute__((ext_vector_type(8)));
typedef __fp16 h16x2 __attribute__((ext_vector_type(2)));  // cvt_pkrtz return type
typedef float f32x4 __attribute__((ext_vector_type(4)));

__device__ __forceinline__ f32x4 mfma_qk(bf16x8 a, bf16x8 b, f32x4 c) {
    return __builtin_amdgcn_mfma_f32_16x16x32_bf16(a, b, c, 0, 0, 0);
}
// full-rate K=32 f16 MFMA for PV (legacy 16x16x16 runs at half rate)
__device__ __forceinline__ f32x4 mfma_pv32(f16x8 a, f16x8 b, f32x4 c) {
    return __builtin_amdgcn_mfma_f32_16x16x32_f16(a, b, c, 0, 0, 0);
}
// pack two f32 -> f16x2 via v_cvt_pkrtz (bit-identical retype of __fp16 result)
__device__ __forceinline__ f16x2 pkrtz(float a, float b) {
    h16x2 r = __builtin_amdgcn_cvt_pkrtz(a, b);
    return __builtin_bit_cast(f16x2, r);
}

// async global -> LDS, 16 bytes per lane (dest = wave-uniform base + lane*16)
#define GLOAD_LDS16(gp, lp)                                                    \
    __builtin_amdgcn_global_load_lds(                                          \
        (const __attribute__((address_space(1))) unsigned int*)(gp),           \
        (__attribute__((address_space(3))) unsigned int*)(lp), 16, 0, 0)

// counted pipeline waits: oldest stage complete, newest stays in flight.
// NEVER vmcnt(0) in a main loop (T4).
#define PWAIT2 asm volatile("s_waitcnt vmcnt(2) lgkmcnt(0)\ns_barrier" ::: "memory")
#define PWAIT0 asm volatile("s_waitcnt vmcnt(0) lgkmcnt(0)\ns_barrier" ::: "memory")

// ---------------------------------------------------------------------------
// Cast fp32 -> bf16: 4 weights (1024^2 each), key_value (8M), query (8M).
// Wq is pre-scaled by 1/sqrt(HD)=0.125 (EXACT in bf16: exponent shift).
// R12: reverted to the R10 configuration (R11's grid-stride x4 was part of a
// -8.7 µs net regression; reverting to the measured-best anchor).
// ---------------------------------------------------------------------------
__global__ __launch_bounds__(256) void cast_inputs(
    const float* __restrict__ w0, const float* __restrict__ w1,
    const float* __restrict__ w2, const float* __restrict__ w3,
    const float* __restrict__ kv, const float* __restrict__ q,
    bf16* __restrict__ Wb, bf16* __restrict__ KVa, bf16* __restrict__ Qb) {
    long i4 = (long)blockIdx.x * 256 + threadIdx.x;  // float4 index
    const float* src;
    bf16* dst;
    long loc;
    float sc = 1.0f;
    if (i4 < 1048576) {            // 4 weights x 262144 float4
        int which = (int)(i4 >> 18);
        loc = (i4 & 262143) << 2;
        src = which == 0 ? w0 : which == 1 ? w1 : which == 2 ? w2 : w3;
        dst = Wb + ((long)which << 20);
        if (which == 0) sc = 0.125f;
    } else if (i4 < 3145728) {     // key_value
        loc = (i4 - 1048576) << 2;
        src = kv; dst = KVa;
    } else {                       // query
        loc = (i4 - 3145728) << 2;
        src = q; dst = Qb;
    }
    float4 f = *(const float4*)(src + loc);
    bf16x4 o;
    o[0] = (bf16)(f.x * sc); o[1] = (bf16)(f.y * sc);
    o[2] = (bf16)(f.z * sc); o[3] = (bf16)(f.w * sc);
    *(bf16x4*)(dst + loc) = o;
}

// ---------------------------------------------------------------------------
// Core GEMM: C[M,N] = A[M,K] @ W[N,K]^T + bias*bsc. M=8192, N=K=1024.
// R12: 512 threads / 8 waves per block — pure-TLP change (R9/R10/R11 showed
// schedule and tile-shape variants are null; TLP never isolated). Same 128²
// tile, same BK=32 triple-buffer counted-vmcnt pipeline, same LDS (3x16KB),
// same traffic; waves/CU doubles (proj: 12->24, gemm_o: 8->16). Wave grid
// 2M x 4N, each wave 64x32 (acc 4x2). Staging simplifies to 2 gloads/stage
// (512 lanes x 16B = 8KB buffer) -> PWAIT2, identical invariant to attn's
// verified pipeline. Per-element K-accumulation order unchanged (output
// bitwise identical to R10).
// LDS per buffer b (base b*16384): A slot(r,s)=r*4+s holds chunk s^(r&3),
// 16B slots; B at +8192. Fragment chunk for k=quad*8+j is slot quad^(r&3).
// om: 0 = bf16 row-major, 1 = f32 row-major,
// om: 2 = f16 V^T [b,h,d,skv] with kv PERMUTED per 32-block:
//         chunk g (g=0..3) holds kv = 32B + {4g..4g+3, 16+4g..16+4g+3}
//         so the attn PV A-fragment is a single contiguous f16x8.
// ---------------------------------------------------------------------------
__device__ __forceinline__ void gemm_core(
    const bf16* __restrict__ A, const bf16* __restrict__ Wt,
    const float* __restrict__ bias, void* __restrict__ Yv,
    const int om, bf16* smem, const int n0, const int m0, const float bsc) {
    constexpr int Kd = 1024, Nd = 1024;
    constexpr int TP = 132;  // om2 transpose row stride
    char* sbytes = (char*)smem;
    const int tid = threadIdx.x;             // 0..511
    const int wid = tid >> 6, lane = tid & 63;
    const int l16 = lane & 15, quad = lane >> 4;
    const int mh = (wid >> 2) * 64, nh = (wid & 3) * 32;

    // staging: lane covers row rS=tid>>2 (0..127), chunk c4=(tid&3)^(rS&3)
    const int rS = tid >> 2;
    const int cS = (tid & 3) ^ (rS & 3);
    const bf16* Asrc = A + (long)(m0 + rS) * Kd + cS * 8;
    const bf16* Bsrc = Wt + (long)(n0 + rS) * Kd + cS * 8;

    // fragment LDS byte offsets (lane part; + i*1024 imm + buffer base).
    // row = mh|nh + i*16 + l16; (i*16)&3==0 so row&3 == l16&3.
    const int aOff = (mh + l16) * 64 + ((quad ^ (l16 & 3)) << 4);
    const int bOff = 8192 + (nh + l16) * 64 + ((quad ^ (l16 & 3)) << 4);

    f32x4 acc[4][2];
#pragma unroll
    for (int i = 0; i < 4; ++i)
#pragma unroll
        for (int j = 0; j < 2; ++j) acc[i][j] = (f32x4){0.f, 0.f, 0.f, 0.f};

    auto stageK = [&](int step, int b) {
        const int kt = step * 32;
        char* base = sbytes + b * 16384;
        GLOAD_LDS16(Asrc + kt, base + tid * 16);
        GLOAD_LDS16(Bsrc + kt, base + 8192 + tid * 16);
    };

    auto computeK = [&](int b) {
        const char* base = sbytes + b * 16384;
        bf16x8 af[4], bq[2];
#pragma unroll
        for (int i = 0; i < 4; ++i) af[i] = *(const bf16x8*)(base + aOff + i * 1024);
#pragma unroll
        for (int i = 0; i < 2; ++i) bq[i] = *(const bf16x8*)(base + bOff + i * 1024);
#pragma unroll
        for (int i = 0; i < 4; ++i)
#pragma unroll
            for (int j = 0; j < 2; ++j)
                acc[i][j] = mfma_qk(af[i], bq[j], acc[i][j]);
    };

    // depth-2 pipeline over 32 K-steps, 3 buffers, counted vmcnt(2).
    stageK(0, 0);
    stageK(1, 1);
#pragma unroll 1
    for (int t = 0; t < 30; t += 3) {
        PWAIT2; stageK(t + 2, 2); computeK(0);
        PWAIT2; stageK(t + 3, 0); computeK(1);
        PWAIT2; stageK(t + 4, 1); computeK(2);
    }
    PWAIT2; computeK(0);   // step 30; step 31's loads in flight
    PWAIT0; computeK(1);   // step 31
    __syncthreads();       // all LDS reads done before epilogue overlay

    if (om == 2) {
        // transpose tile through LDS as f16, then coalesced 16B stores with
        // the per-32-block kv-group permutation applied on the way out.
#pragma unroll
        for (int j = 0; j < 2; ++j) {
            const int col = nh + j * 16 + l16;
            const float bv = bias[n0 + col] * bsc;
#pragma unroll
            for (int i = 0; i < 4; ++i)
#pragma unroll
                for (int p = 0; p < 2; ++p) {
                    f16x2 pk2;
                    pk2[0] = (f16)(acc[i][j][p * 2 + 0] + bv);
                    pk2[1] = (f16)(acc[i][j][p * 2 + 1] + bv);
                    *(f16x2*)&smem[col * TP + mh + i * 16 + quad * 4 + p * 2] = pk2;
                }
        }
        __syncthreads();
        // Vt[((b*16+h)*64+d)*2048 + skv], permuted within each 32-kv block.
        // 512 threads: tid = g*16 + rowc, g in [0,32); c<4 -> col = g + c*32
        // (bijective onto 128 cols x 16 chunks).
        const int b_ = m0 >> 11, skv0 = m0 & 2047;
        const int rowc = tid & 15;
        const int B32 = (rowc >> 2) * 32, g4 = (rowc & 3) * 4;
        const f16* sm = (const f16*)smem;
#pragma unroll
        for (int c = 0; c < 4; ++c) {
            const int col = (tid >> 4) + c * 32;
            const int colg = n0 + col;
            f16x4 lo = *(const f16x4*)&sm[col * TP + B32 + g4];
            f16x4 hi = *(const f16x4*)&sm[col * TP + B32 + 16 + g4];
            f16x8 v = __builtin_shufflevector(lo, hi, 0, 1, 2, 3, 4, 5, 6, 7);
            const long base = ((long)((b_ * 16 + (colg >> 6)) * 64 + (colg & 63))) << 11;
            *(f16x8*)((f16*)Yv + base + skv0 + rowc * 8) = v;
        }
    } else {
#pragma unroll
        for (int j = 0; j < 2; ++j) {
            const int col = n0 + nh + j * 16 + l16;
            const float bv = bias[col] * bsc;
#pragma unroll
            for (int i = 0; i < 4; ++i)
#pragma unroll
                for (int r = 0; r < 4; ++r) {
                    int row = m0 + mh + i * 16 + quad * 4 + r;
                    float v = acc[i][j][r] + bv;
                    if (om == 1)
                        ((float*)Yv)[(long)row * Nd + col] = v;
                    else
                        ((bf16*)Yv)[(long)row * Nd + col] = (bf16)v;
                }
        }
    }
}

// Fused Q/K/V projections: one 1536-block launch, 512 threads (24 waves/CU).
// Chunked bijective XCD swizzle keeps A-panel / W reuse in one L2.
__global__ __launch_bounds__(512) void proj_qkv(
    const bf16* __restrict__ Qb, const bf16* __restrict__ KVa,
    const bf16* __restrict__ Wb,
    const float* __restrict__ bq, const float* __restrict__ bk,
    const float* __restrict__ bv,
    bf16* __restrict__ Qw, bf16* __restrict__ Kw, f16* __restrict__ Vt) {
    __shared__ __align__(16) bf16 smem[24576];  // 49152 B: 3 pipeline bufs / TP overlay
    const int lin = blockIdx.x + (blockIdx.y << 3) + (blockIdx.z << 9);  // 0..1535
    const int nid = (lin & 7) * 192 + (lin >> 3);
    const int z = nid >> 9, rem = nid & 511;
    const int n0 = (rem & 7) << 7, m0 = (rem >> 3) << 7;
    if (z == 0)
        gemm_core(Qb, Wb, bq, Qw, 0, smem, n0, m0, 0.125f);  // Wq pre-scaled
    else if (z == 1)
        gemm_core(KVa, Wb + (1l << 20), bk, Kw, 0, smem, n0, m0, 1.0f);
    else
        gemm_core(KVa, Wb + (2l << 20), bv, Vt, 2, smem, n0, m0, 1.0f);
}

__global__ __launch_bounds__(512) void gemm_o(
    const bf16* __restrict__ Cw, const bf16* __restrict__ Wo,
    const float* __restrict__ bo, float* __restrict__ out) {
    __shared__ __align__(16) bf16 smem[24576];
    const int lin = blockIdx.x + (blockIdx.y << 3);  // 0..511
    const int nid = (lin & 7) * 64 + (lin >> 3);
    gemm_core(Cw, Wo, bo, out, 1, smem, (nid & 7) << 7, (nid >> 3) << 7, 1.0f);
}

// ---------------------------------------------------------------------------
// StableMax cross-attention, transposed-score formulation.
// Attn = the R6 kernel (106-108 µs measured best; 94% combined issue-slot
// saturation). R8's rcp-combine was a cycle-accounting wash (rcp 128->32 cyc
// but +104 cyc muls/adds + serial chain -> 117.8). Do not re-try VALU
// restructures without an issue-cycle budget showing >20% net cut.
// Structure: KVB=32, triple-buffered depth-2 pipeline, vmcnt(2) counted
// waits, 24KB LDS, zero-VALU LDS addressing, pkrtz P-pack, ones-MFMA den,
// scores pre-scaled via Wq/8.
// NOTE: plain __launch_bounds__(256) — adding ",4" min-occupancy clamped the
// allocator to 64 VGPRs and spilled to scratch (R1: 1.2GB HBM writes, 4x
// slowdown). Do not re-add.
// ---------------------------------------------------------------------------
__global__ __launch_bounds__(256) void attn_kernel(
    const bf16* __restrict__ Q, const bf16* __restrict__ K,
    const f16* __restrict__ Vt, bf16* __restrict__ C) {
    constexpr int E = 1024, S = 2048;
    __shared__ __align__(16) char smem_raw[24576];  // 3 bufs x (4KB K + 4KB V)

    const int tid = threadIdx.x;
    const int wid = tid >> 6, lane = tid & 63;
    const int l16 = lane & 15, quad = lane >> 4;
    const int l7 = l16 & 7, l3 = l16 & 3;
    const int lin = blockIdx.x + (blockIdx.y << 4) + (blockIdx.z << 8);
    const int nid = (lin & 7) * 128 + (lin >> 3);
    const int qt = nid & 15, h = (nid >> 4) & 15, b = nid >> 8;

    const long q0 = (long)b * S + qt * 128;
    const bf16* Qg = Q + q0 * E + h * 64;
    const bf16* Kg = K + (long)b * S * E + h * 64;
    const f16* Vg = Vt + ((long)(b * 16 + h) << 17);  // [64 d][2048 kv] permuted

    bf16x8 qf[2][2];
#pragma unroll
    for (int mt = 0; mt < 2; ++mt)
#pragma unroll
        for (int kc = 0; kc < 2; ++kc)
            qf[mt][kc] = *(const bf16x8*)(Qg + (long)(wid * 32 + mt * 16 + l16) * E + kc * 32 + quad * 8);
    asm volatile("s_waitcnt vmcnt(0)" ::: "memory");

    const bf16* Ksrc = Kg + (long)(tid >> 3) * E + (((tid & 7) ^ ((tid >> 3) & 7)) * 8);
    const f16* Vsrc = Vg + (long)(tid >> 2) * S + (((tid & 3) ^ ((tid >> 2) & 3)) * 8);

    int ka0[3], ka1[3], va[3];
#pragma unroll
    for (int i = 0; i < 3; ++i) {
        ka0[i] = i * 8192 + l16 * 128 + ((quad ^ l7) << 4);
        ka1[i] = i * 8192 + l16 * 128 + (((quad + 4) ^ l7) << 4);
        va[i]  = i * 8192 + 4096 + l16 * 64 + ((quad ^ l3) << 4);
    }

    f16x8 ones8;
#pragma unroll
    for (int j = 0; j < 8; ++j) ones8[j] = (f16)1.0f;

    f32x4 ctx[2][4];   // ctx^T: lane holds d=dt*16+quad*4+r, q=l16
    f32x4 dacc[2];     // ones-MFMA denominator accumulator (rows identical)
#pragma unroll
    for (int mt = 0; mt < 2; ++mt) {
        dacc[mt] = (f32x4){0.f, 0.f, 0.f, 0.f};
#pragma unroll
        for (int dt = 0; dt < 4; ++dt) ctx[mt][dt] = (f32x4){0.f, 0.f, 0.f, 0.f};
    }

    auto stage = [&](int kv0, int bi) {
        GLOAD_LDS16(Ksrc + (long)kv0 * E, smem_raw + bi * 8192 + tid * 16);
        GLOAD_LDS16(Vsrc + kv0, smem_raw + bi * 8192 + 4096 + tid * 16);
    };

    auto compute = [&](int bi) {
        f32x4 sacc[2][2];  // [sh][mt]
#pragma unroll
        for (int sh = 0; sh < 2; ++sh) {
            bf16x8 kf0 = *(const bf16x8*)(smem_raw + ka0[bi] + sh * 2048);
            bf16x8 kf1 = *(const bf16x8*)(smem_raw + ka1[bi] + sh * 2048);
            __builtin_amdgcn_s_setprio(1);
#pragma unroll
            for (int mt = 0; mt < 2; ++mt) {
                f32x4 t = mfma_qk(kf0, qf[mt][0], (f32x4){0.f, 0.f, 0.f, 0.f});
                sacc[sh][mt] = mfma_qk(kf1, qf[mt][1], t);
            }
            __builtin_amdgcn_s_setprio(0);
        }
        f16x8 pp[2];
#pragma unroll
        for (int mt = 0; mt < 2; ++mt) {
            float sv[8];
#pragma unroll
            for (int sh = 0; sh < 2; ++sh)
#pragma unroll
                for (int r = 0; r < 4; ++r) {
                    float x = sacc[sh][mt][r];
                    float u = __builtin_fabsf(x) + 1.0f;
                    sv[sh * 4 + r] = (x >= 0.f) ? u : __builtin_amdgcn_rcpf(u);
                }
            f16x2 w0 = pkrtz(sv[0], sv[1]);
            f16x2 w1 = pkrtz(sv[2], sv[3]);
            f16x2 w2 = pkrtz(sv[4], sv[5]);
            f16x2 w3 = pkrtz(sv[6], sv[7]);
            f16x4 lo = __builtin_shufflevector(w0, w1, 0, 1, 2, 3);
            f16x4 hi = __builtin_shufflevector(w2, w3, 0, 1, 2, 3);
            pp[mt] = __builtin_shufflevector(lo, hi, 0, 1, 2, 3, 4, 5, 6, 7);
        }
        __builtin_amdgcn_s_setprio(1);
        dacc[0] = mfma_pv32(ones8, pp[0], dacc[0]);
        dacc[1] = mfma_pv32(ones8, pp[1], dacc[1]);
        __builtin_amdgcn_s_setprio(0);
#pragma unroll
        for (int dt = 0; dt < 4; ++dt) {
            f16x8 vf = *(const f16x8*)(smem_raw + va[bi] + dt * 1024);
            __builtin_amdgcn_s_setprio(1);
#pragma unroll
            for (int mt = 0; mt < 2; ++mt)
                ctx[mt][dt] = mfma_pv32(vf, pp[mt], ctx[mt][dt]);
            __builtin_amdgcn_s_setprio(0);
        }
    };

    stage(0, 0);
    stage(32, 1);
    int kv = 64;
#pragma unroll 1
    for (int it = 0; it < 20; ++it) {
        PWAIT2; stage(kv, 2); compute(0); kv += 32;
        PWAIT2; stage(kv, 0); compute(1); kv += 32;
        PWAIT2; stage(kv, 1); compute(2); kv += 32;
    }
    PWAIT2; stage(kv, 2); compute(0);        // t=60, stage tile 62
    PWAIT2; stage(kv + 32, 0); compute(1);   // t=61, stage tile 63
    PWAIT2; compute(2);                      // t=62
    PWAIT0; compute(0);                      // t=63
    __syncthreads();

    float scl[2];
#pragma unroll
    for (int mt = 0; mt < 2; ++mt) scl[mt] = __builtin_amdgcn_rcpf(dacc[mt][0]);

    bf16* Os = (bf16*)smem_raw;
#pragma unroll
    for (int mt = 0; mt < 2; ++mt)
#pragma unroll
        for (int dt = 0; dt < 4; ++dt) {
            bf16x4 o;
#pragma unroll
            for (int r = 0; r < 4; ++r) o[r] = (bf16)(ctx[mt][dt][r] * scl[mt]);
            *(bf16x4*)&Os[(wid * 32 + mt * 16 + l16) * 68 + dt * 16 + quad * 4] = o;
        }
    __syncthreads();
    {
        const int r = tid >> 1, c = (tid & 1) * 32;
        bf16* cp = C + (q0 + r) * E + h * 64 + c;
#pragma unroll
        for (int j = 0; j < 4; ++j)
            *(bf16x8*)(cp + j * 8) = *(const bf16x8*)&Os[r * 68 + c + j * 8];
    }
}

// ---------------------------------------------------------------------------
extern "C" void kernel_launch(void* const* d_in, const int* in_sizes, int n_in,
                              void* d_out, int out_size, void* d_ws, size_t ws_size,
                              hipStream_t stream) {
    const float* query = (const float*)d_in[0];
    const float* keyv  = (const float*)d_in[1];
    const float* Wq = (const float*)d_in[2];
    const float* bq = (const float*)d_in[3];
    const float* Wk = (const float*)d_in[4];
    const float* bk = (const float*)d_in[5];
    const float* Wv = (const float*)d_in[6];
    const float* bv = (const float*)d_in[7];
    const float* Wo = (const float*)d_in[8];
    const float* bo = (const float*)d_in[9];

    char* ws = (char*)d_ws;
    bf16* Wb  = (bf16*)ws;                  // 8 MB: Wq/8,Wk,Wv,Wo bf16
    bf16* KVa = (bf16*)(ws + (8l << 20));   // 16 MB kv bf16 (later Cw)
    bf16* Qb  = (bf16*)(ws + (24l << 20));  // 16 MB query bf16
    bf16* Qw  = (bf16*)(ws + (40l << 20));  // 16 MB (holds q/8)
    f16*  Vt  = (f16*)(ws + (56l << 20));   // 16 MB V^T f16 [b,h,d,skv] permuted
    bf16* Kw  = (bf16*)d_out;               // d_out dead until gemm_o: use as Kw
    bf16* Cw  = KVa;                        // alias: KVa dead after proj_qkv

    cast_inputs<<<20480, 256, 0, stream>>>(Wq, Wk, Wv, Wo, keyv, query, Wb, KVa, Qb);

    proj_qkv<<<dim3(8, 64, 3), 512, 0, stream>>>(Qb, KVa, Wb, bq, bk, bv, Qw, Kw, Vt);

    attn_kernel<<<dim3(16, 16, 4), 256, 0, stream>>>(Qw, Kw, Vt, Cw);

    gemm_o<<<dim3(8, 64), 512, 0, stream>>>(Cw, Wb + (3l << 20), bo, (float*)d_out);
}